// Round 18
// baseline (254.381 us; speedup 1.0000x reference)
//
#include <hip/hip_runtime.h>

typedef _Float16 f16;
typedef __attribute__((ext_vector_type(8)))  _Float16 f16x8;
typedef __attribute__((ext_vector_type(4)))  _Float16 f16x4;
typedef __attribute__((ext_vector_type(4)))  float    f32x4;
typedef __attribute__((ext_vector_type(16))) float    f32x16;
typedef __attribute__((ext_vector_type(4)))  int      i32x4;

#define MFMA_F16(a,b,c) __builtin_amdgcn_mfma_f32_16x16x32_f16((a),(b),(c),0,0,0)
#define MFMA32(a,b,c)   __builtin_amdgcn_mfma_f32_32x32x16_f16((a),(b),(c),0,0,0)
#define EXP2(x)         __builtin_amdgcn_exp2f(x)   // bare v_exp_f32 (no OCML wrapper)

// problem constants
constexpr int Bc   = 4;
constexpr int Sc   = 2048;
constexpr int Hc   = 12;
constexpr int Dc   = 100;
constexpr int HIDc = 1200;
constexpr int BH   = Bc * Hc;    // 48
constexpr int DP   = 128;        // padded head dim (dim 100 carries the bias trick)
constexpr int LDK  = 1216;       // padded inner dim for x16/w16 (19 * 64)
constexpr int NWP  = 1280;       // padded row count per weight section
constexpr int KVT  = 64;         // kv tile length
constexpr int NT   = Sc / KVT;   // 32 tiles per (b,h)
constexpr int TE   = KVT * DP;   // 8192 elems per K or V tile (16 KB)
constexpr int NKT  = LDK / 64;   // 19 K-tiles in the GEMMs

// merged prep kernel block ranges (256 threads each, exact division)
constexpr int NBX  = (Bc * Sc) * LDK / 4 / 256;       // 9728  (x convert)
constexpr int NBW1 = NWP * LDK / 4 / 256;             // 1520  (per weight)
constexpr int NBW  = 4 * NBW1;                        // 6080
constexpr int NBQK = BH * Sc * 7 / 256;               // 2688  (Q+K pads, f16x4 quads)
constexpr int NBV2 = BH * NT * 28 * 8 / 256;          // 1344  (V pads, f16x8 octets)

// async global->LDS, 16B per lane (linear dest = base + lane*16)
typedef const __attribute__((address_space(1))) void GV;
typedef __attribute__((address_space(3))) void LV;
__device__ __forceinline__ void gload16(const f16* g, f16* l) {
    __builtin_amdgcn_global_load_lds((GV*)g, (LV*)l, 16, 0, 0);
}

// ---------------- merged prep: x cvt | 4x w cvt | QK pads | V pads ----------
// (R17-proven) Pads vectorized: swizzle XORs touch only bits >=3, so 4-wide
// d-quads (K) and 8-wide t-octets (V) stay contiguous -> f16x4/f16x8 stores.
__global__ void prep_kernel(const float* __restrict__ x,
                            const float* __restrict__ w0, const float* __restrict__ w1,
                            const float* __restrict__ w2, const float* __restrict__ w3,
                            f16* __restrict__ x16,
                            f16* __restrict__ d0p, f16* __restrict__ d1p,
                            f16* __restrict__ d2p, f16* __restrict__ d3p,
                            f16* __restrict__ q, f16* __restrict__ kT, f16* __restrict__ vT,
                            const float* __restrict__ alibi, const float* __restrict__ amask,
                            const int* __restrict__ lidx) {
    const int bid = blockIdx.x;
    if (bid < NBX) {
        int i = bid * 256 + threadIdx.x;
        int idx = i * 4;
        int r = idx / LDK, c = idx - r * LDK;
        f16x4 o;
        if (c + 3 < HIDc) {
            float4 v = *(const float4*)(x + (size_t)r * HIDc + c);
            o[0] = (f16)v.x; o[1] = (f16)v.y; o[2] = (f16)v.z; o[3] = (f16)v.w;
        } else {
#pragma unroll
            for (int e = 0; e < 4; ++e)
                o[e] = (f16)((c + e < HIDc) ? x[(size_t)r * HIDc + c + e] : 0.f);
        }
        *(f16x4*)(x16 + idx) = o;
    } else if (bid < NBX + NBW) {
        int lb = bid - NBX;
        int which = lb / NBW1;
        int i = (lb - which * NBW1) * 256 + threadIdx.x;
        const float* src = (which == 0) ? w0 : (which == 1) ? w1 : (which == 2) ? w2 : w3;
        f16* dst = (which == 0) ? d0p : (which == 1) ? d1p : (which == 2) ? d2p : d3p;
        int idx = i * 4;
        int r = idx / LDK, c = idx - r * LDK;
        f16x4 o;
        if (r < HIDc && c + 3 < HIDc) {
            float4 v = *(const float4*)(src + (size_t)r * HIDc + c);
            o[0] = (f16)v.x; o[1] = (f16)v.y; o[2] = (f16)v.z; o[3] = (f16)v.w;
        } else {
#pragma unroll
            for (int e = 0; e < 4; ++e)
                o[e] = (f16)((r < HIDc && c + e < HIDc) ? src[(size_t)r * HIDc + c + e] : 0.f);
        }
        *(f16x4*)(dst + idx) = o;
    } else if (bid < NBX + NBW + NBQK) {
        int i = (bid - NBX - NBW) * 256 + threadIdx.x;
        int qd = i % 7;
        int rs = i / 7;                             // bh*S + t
        int d0 = Dc + 4 * qd;                       // 100,104,...,124
        int bh = rs >> 11, t = rs & (Sc - 1);
        f16x4 oq = {(f16)0.f, (f16)0.f, (f16)0.f, (f16)0.f};
        f16x4 ok = {(f16)0.f, (f16)0.f, (f16)0.f, (f16)0.f};
        if (qd == 0) {
            int b = bh / Hc;
            float bias = alibi[rs] * 0.1f + amask[b * Sc + t] * ((float)(lidx[0] + 1) * 0.1f);
            oq[0] = (f16)1.0f;
            ok[0] = (f16)bias;
        }
        *(f16x4*)(q + (size_t)rs * DP + d0) = oq;
        const size_t tb = ((size_t)bh * NT + (t >> 6)) * TE;
        *(f16x4*)(kT + tb + (t & 63) * DP + (d0 ^ ((t & 15) << 3))) = ok;
    } else {
        int i = (bid - NBX - NBW - NBQK) * 256 + threadIdx.x;
        int oct  = i & 7;
        int rest = i >> 3;
        int d28  = rest % 28;
        int r2   = rest / 28;
        int tile = r2 & (NT - 1);
        int bh   = r2 >> 5;
        int d    = Dc + d28;
        const size_t tb = ((size_t)bh * NT + tile) * TE;
        f16x8 z = {(f16)0.f, (f16)0.f, (f16)0.f, (f16)0.f,
                   (f16)0.f, (f16)0.f, (f16)0.f, (f16)0.f};
        *(f16x8*)(vT + tb + d * 64 + ((oct * 8) ^ ((d & 7) << 3))) = z;
    }
}

// ---------------- 256x256 deep-pipelined B^T GEMM (T3 schedule) -------------
// R16 A-band mapping + OPERAND-SWAPPED MFMA (R10's epilogue, exonerated by the
// R10/R11 bit-identical-absmax evidence): acc = mfma(bf, af, acc) -> lane holds
// m = ...+n15 (fixed), n = ...+4g+r (consecutive quad) -> packed stores.
// Quad safety: n0 % 4 == 0 and 100 % 4 == 0, 1280 % 4 == 0 -> a quad never
// crosses a head or section boundary; K swizzle XOR uses bits 3-6 only.
// mode 0: fused QKV scatter (B = [wq16;wk16;wv16], N=3840)
// mode 1: f32 row-major M x 1200 (final out), float4 stores
__launch_bounds__(512)
__global__ void gemm256_kernel(const f16* __restrict__ A, int lda,
                               const f16* __restrict__ Bm,
                               f16* __restrict__ outQ,
                               f16* __restrict__ outK,
                               f16* __restrict__ outV,
                               float* __restrict__ oF,
                               int nbx, int mode) {
    __shared__ f16 As[2][256][64];   // 64 KB
    __shared__ f16 Bs[2][256][64];   // 64 KB

    const int tid  = threadIdx.x;
    const int lane = tid & 63, wid = tid >> 6;
    const int wm = wid >> 2, wn = wid & 3;       // 2x4 wave grid, 128x64 per wave
    const int n15 = lane & 15, g = lane >> 4;
    const int sx  = (n15 & 7) << 3;              // read-side XOR (row&7 == n15&7)

    // XCD A-band mapping (bijective): bx = xcd*4 + (s&3), by = s>>2
    const int s  = (int)blockIdx.x >> 3;
    const int bx = ((int)blockIdx.x & 7) * 4 + (s & 3);
    const int by = s >> 2;
    const int brow = bx * 256, bcol = by * 256;

    f32x4 acc[8][4];
#pragma unroll
    for (int i = 0; i < 8; ++i)
#pragma unroll
        for (int j = 0; j < 4; ++j)
            acc[i][j] = (f32x4){0.f, 0.f, 0.f, 0.f};

    const f16* Ab = A  + (size_t)brow * lda;
    const f16* Bb = Bm + (size_t)bcol * LDK;

    // prologue: stage tile 0 into buf 0 (A 4 chunks + B 4 chunks per thread)
#pragma unroll
    for (int j = 0; j < 4; ++j) {
        const int c = j * 512 + tid;             // 2048 chunks of 16B
        const int row = c >> 3;
        const int co  = ((c & 7) ^ (row & 7)) * 8;
        gload16(Ab + (size_t)row * lda + co, &As[0][0][0] + c * 8);
    }
#pragma unroll
    for (int j = 0; j < 4; ++j) {
        const int c = j * 512 + tid;
        const int row = c >> 3;
        const int co  = ((c & 7) ^ (row & 7)) * 8;
        gload16(Bb + (size_t)row * LDK + co, &Bs[0][0][0] + c * 8);
    }

    for (int kt = 0; kt < NKT; ++kt) {
        const int bsel = kt & 1;
        const int k1 = (kt + 1) << 6;
        // iteration entry: tile kt's 8 loads landed (all waves), prev reads done
        asm volatile("s_waitcnt vmcnt(0)" ::: "memory");
        __builtin_amdgcn_s_barrier();
        __builtin_amdgcn_sched_barrier(0);

#pragma unroll
        for (int ph = 0; ph < 4; ++ph) {
            const int mh = ph >> 1, nh = ph & 1;
            if (ph) __builtin_amdgcn_s_barrier();

            // ds_read this quadrant's fragments (compiler emits fine lgkmcnt)
            f16x8 af[2][4], bf[2][2];
#pragma unroll
            for (int kc = 0; kc < 2; ++kc) {
                const int col = (kc * 32 + g * 8) ^ sx;
#pragma unroll
                for (int mf = 0; mf < 4; ++mf)
                    af[kc][mf] = *(const f16x8*)&As[bsel][wm * 128 + mh * 64 + mf * 16 + n15][col];
#pragma unroll
                for (int nf = 0; nf < 2; ++nf)
                    bf[kc][nf] = *(const f16x8*)&Bs[bsel][wn * 64 + nh * 32 + nf * 16 + n15][col];
            }

            // stage next K-tile early (phases 0-1) into buf^1
            if (kt + 1 < NKT) {
                if (ph == 0) {
#pragma unroll
                    for (int j = 0; j < 4; ++j) {
                        const int c = j * 512 + tid;
                        const int row = c >> 3;
                        const int co  = ((c & 7) ^ (row & 7)) * 8;
                        gload16(Ab + (size_t)row * lda + k1 + co, &As[bsel ^ 1][0][0] + c * 8);
                    }
                } else if (ph == 1) {
#pragma unroll
                    for (int j = 0; j < 4; ++j) {
                        const int c = j * 512 + tid;
                        const int row = c >> 3;
                        const int co  = ((c & 7) ^ (row & 7)) * 8;
                        gload16(Bb + (size_t)row * LDK + k1 + co, &Bs[bsel ^ 1][0][0] + c * 8);
                    }
                }
            }

            __builtin_amdgcn_s_setprio(1);
#pragma unroll
            for (int kc = 0; kc < 2; ++kc)
#pragma unroll
                for (int mf = 0; mf < 4; ++mf)
#pragma unroll
                    for (int nf = 0; nf < 2; ++nf)
                        acc[mh * 4 + mf][nh * 2 + nf] =
                            MFMA_F16(bf[kc][nf], af[kc][mf], acc[mh * 4 + mf][nh * 2 + nf]);
            __builtin_amdgcn_s_setprio(0);
        }
    }

    // epilogue (swapped layout): m = brow + wm*128 + mi*16 + n15 (1 row/lane),
    // n = bcol + wn*64 + ni*16 + 4g + r (consecutive quad)
#pragma unroll
    for (int mi = 0; mi < 8; ++mi) {
        const int m = brow + wm * 128 + mi * 16 + n15;
        const int b = m >> 11;
        const int sq = m & (Sc - 1);
#pragma unroll
        for (int ni = 0; ni < 4; ++ni) {
            const int n0 = bcol + wn * 64 + ni * 16 + g * 4;
            if (mode == 1) {
                if (n0 >= HIDc) continue;
                float4 v = {acc[mi][ni][0], acc[mi][ni][1], acc[mi][ni][2], acc[mi][ni][3]};
                *(float4*)(oF + (size_t)m * HIDc + n0) = v;
            } else {
                const int which = (n0 >= 2560) ? 2 : (n0 >= 1280 ? 1 : 0);
                const int nn0 = n0 - which * 1280;
                if (nn0 >= HIDc) continue;
                const int h = nn0 / 100, d0 = nn0 - h * 100;   // quad stays in head h
                if (which == 0) {
                    f16x4 pk;
#pragma unroll
                    for (int r = 0; r < 4; ++r) pk[r] = (f16)acc[mi][ni][r];
                    *(f16x4*)(outQ + ((size_t)(b * Hc + h) * Sc + sq) * DP + d0) = pk;
                } else if (which == 1) {
                    const size_t tb = ((size_t)(b * Hc + h) * NT + (sq >> 6)) * TE;
                    f16x4 pk;
#pragma unroll
                    for (int r = 0; r < 4; ++r) pk[r] = (f16)acc[mi][ni][r];
                    // XOR uses bits 3-6 only; d0 % 4 == 0 -> quad contiguous
                    *(f16x4*)(outK + tb + (sq & 63) * DP + (d0 ^ ((sq & 15) << 3))) = pk;
                } else {
                    const size_t tb = ((size_t)(b * Hc + h) * NT + (sq >> 6)) * TE;
#pragma unroll
                    for (int r = 0; r < 4; ++r) {
                        const int d = d0 + r;
                        outV[tb + d * 64 + ((sq & 63) ^ ((d & 7) << 3))] = (f16)acc[mi][ni][r];
                    }
                }
            }
        }
    }
}

// ---------------- fused flash attention (R13 base + ZRO-hoist + tree-sum) ---
// grid 768 1-D, XCD-swizzled. 4 waves/block, 32 q-rows each (q = lane&31).
// 2 barriers/tile; ledger: entry {K(t) 4, V(t) 4, K(t+1) 4} -> vmcnt(4).
// R14 lesson: unified VGPR+AGPR ~150 regs -> 3 waves/SIMD is the optimum.
// R18 deltas (math-identical): (a) hoisted never-written ZRO as first-MFMA
// C-input (kills 32 zero-init v_movs/tile); (b) tree-structured ps sum.
__launch_bounds__(256, 3)
__global__ void attn_kernel(const f16* __restrict__ Qp, const f16* __restrict__ KpT,
                            const f16* __restrict__ VpT, const int* __restrict__ lidx,
                            f16* __restrict__ outp) {
    __shared__ f16 Kl[2][64][128];     // 32 KB, double-buffered, 4-bit swizzle
    __shared__ f16 Vl[128][64];        // 16 KB, 3-bit swizzle

    const int tid  = threadIdx.x;
    const int lane = tid & 63, wave = tid >> 6;
    const int l31 = lane & 31, h = lane >> 5;
    const int sxk = (l31 & 15) << 3;   // K read XOR ((t&15) == (l31&15))
    const int sxv = (l31 & 7) << 3;    // V read XOR ((d&7) == (l31&7))

    const int bid = blockIdx.x;
    const int bh  = (bid & 7) * 6 + ((bid >> 3) >> 4);
    const int qt  = (bid >> 3) & 15;
    const int qr0 = qt * 128 + wave * 32;

    // log2-domain scale: exp(s*10/(L+1)) == exp2(s*10*log2e/(L+1))
    const float scale = 10.f * 1.44269504f / (float)(lidx[0] + 1);

    // Q rows in regs: 7 K-steps cover d=0..111 (d>=112 is structurally zero)
    const f16* Qb = Qp + ((size_t)bh * Sc + qr0 + l31) * DP + h * 8;
    f16x8 qreg[7];
#pragma unroll
    for (int st = 0; st < 7; ++st) {
        f16x8 v = *(const f16x8*)(Qb + st * 16);
#pragma unroll
        for (int e = 0; e < 8; ++e)
            v[e] = (f16)((float)v[e] * scale);
        qreg[st] = v;
    }

    float m_run = -1e30f, l_run = 0.f;
    f32x16 accO[4];                    // O^T block db: d = db*32+(reg&3)+8*(reg>>2)+4h, q=l31
#pragma unroll
    for (int db = 0; db < 4; ++db)
#pragma unroll
        for (int i = 0; i < 16; ++i)
            accO[db][i] = 0.f;

    // never-written zero C-input for the first QK MFMA of each tile
    f32x16 ZRO;
#pragma unroll
    for (int i = 0; i < 16; ++i) ZRO[i] = 0.f;

    const f16* Kbase = KpT + (size_t)bh * NT * TE;
    const f16* Vbase = VpT + (size_t)bh * NT * TE;

    // prologue: K0 -> Kl[0], V0 -> Vl, K1 -> Kl[1]
#pragma unroll
    for (int j = 0; j < 4; ++j) {
        const int c8 = (j * 256 + tid) * 8;
        gload16(Kbase + c8, &Kl[0][0][0] + c8);
    }
#pragma unroll
    for (int j = 0; j < 4; ++j) {
        const int c8 = (j * 256 + tid) * 8;
        gload16(Vbase + c8, &Vl[0][0] + c8);
    }
#pragma unroll
    for (int j = 0; j < 4; ++j) {
        const int c8 = (j * 256 + tid) * 8;
        gload16(Kbase + TE + c8, &Kl[1][0][0] + c8);
    }

    for (int tile = 0; tile < NT; ++tile) {
        const int kb = tile & 1;

        // barrier A: K(t)+V(t) complete (leave K(t+1)'s 4 in flight)
        if (tile == NT - 1) asm volatile("s_waitcnt vmcnt(0)" ::: "memory");
        else                asm volatile("s_waitcnt vmcnt(4)" ::: "memory");
        __builtin_amdgcn_s_barrier();
        __builtin_amdgcn_sched_barrier(0);

        // S^T = K Q^T: lane q=l31, t = tb*32+(reg&3)+8*(reg>>2)+4h
        f32x16 sc0, sc1;
        __builtin_amdgcn_s_setprio(1);
        {
            const int col0 = (h * 8) ^ sxk;
            f16x8 kf0 = *(const f16x8*)&Kl[kb][l31][col0];
            f16x8 kf1 = *(const f16x8*)&Kl[kb][32 + l31][col0];
            sc0 = MFMA32(kf0, qreg[0], ZRO);
            sc1 = MFMA32(kf1, qreg[0], ZRO);
        }
#pragma unroll
        for (int st = 1; st < 7; ++st) {
            const int col = (st * 16 + h * 8) ^ sxk;
            f16x8 kf0 = *(const f16x8*)&Kl[kb][l31][col];
            f16x8 kf1 = *(const f16x8*)&Kl[kb][32 + l31][col];
            sc0 = MFMA32(kf0, qreg[st], sc0);
            sc1 = MFMA32(kf1, qreg[st], sc1);
        }
        __builtin_amdgcn_s_setprio(0);

        // tile max via max3 tree (identical fmax semantics, 5-level depth)
        float mx0 = fmaxf(fmaxf(sc0[0], sc0[1]), sc0[2]);
        float mx1 = fmaxf(fmaxf(sc0[3], sc0[4]), sc0[5]);
        float mx2 = fmaxf(fmaxf(sc0[6], sc0[7]), sc0[8]);
        float mx3 = fmaxf(fmaxf(sc0[9], sc0[10]), sc0[11]);
        float mx4 = fmaxf(fmaxf(sc0[12], sc0[13]), sc0[14]);
        float mx5 = fmaxf(fmaxf(sc0[15], sc1[0]), sc1[1]);
        float mx6 = fmaxf(fmaxf(sc1[2], sc1[3]), sc1[4]);
        float mx7 = fmaxf(fmaxf(sc1[5], sc1[6]), sc1[7]);
        float mx8 = fmaxf(fmaxf(sc1[8], sc1[9]), sc1[10]);
        float mx9 = fmaxf(fmaxf(sc1[11], sc1[12]), sc1[13]);
        float mxa = fmaxf(sc1[14], sc1[15]);
        float nb0 = fmaxf(fmaxf(mx0, mx1), mx2);
        float nb1 = fmaxf(fmaxf(mx3, mx4), mx5);
        float nb2 = fmaxf(fmaxf(mx6, mx7), mx8);
        float nb3 = fmaxf(mx9, mxa);
        float tm = fmaxf(fmaxf(nb0, nb1), fmaxf(nb2, nb3));
        tm = fmaxf(tm, __shfl_xor(tm, 32));

        // defer-max (T13): rescale only when max grew by >8 (log2 domain)
        if (__any(tm > m_run + 8.f)) {
            const float mn = fmaxf(m_run, tm);
            const float al = EXP2(m_run - mn);
            m_run = mn;
            l_run *= al;
#pragma unroll
            for (int db = 0; db < 4; ++db) accO[db] *= al;
        }

        // P = exp2(s - m) in place; row-sum via pairwise tree (depth 5)
#pragma unroll
        for (int i = 0; i < 16; ++i) sc0[i] = EXP2(sc0[i] - m_run);
#pragma unroll
        for (int i = 0; i < 16; ++i) sc1[i] = EXP2(sc1[i] - m_run);
        {
            float t0 = (sc0[0] + sc0[1]) + (sc0[2] + sc0[3]);
            float t1 = (sc0[4] + sc0[5]) + (sc0[6] + sc0[7]);
            float t2 = (sc0[8] + sc0[9]) + (sc0[10] + sc0[11]);
            float t3 = (sc0[12] + sc0[13]) + (sc0[14] + sc0[15]);
            float t4 = (sc1[0] + sc1[1]) + (sc1[2] + sc1[3]);
            float t5 = (sc1[4] + sc1[5]) + (sc1[6] + sc1[7]);
            float t6 = (sc1[8] + sc1[9]) + (sc1[10] + sc1[11]);
            float t7 = (sc1[12] + sc1[13]) + (sc1[14] + sc1[15]);
            float ps = ((t0 + t1) + (t2 + t3)) + ((t4 + t5) + (t6 + t7));
            ps += __shfl_xor(ps, 32);
            l_run += ps;
        }

        // pack P -> PV B-frags: cvt_pkrtz + v_permlane32_swap_b32 (in-register)
        f16x8 pa[4];
        {
            int e0[4], e1[4];
#pragma unroll
            for (int c = 0; c < 4; ++c) {
                auto lo = __builtin_amdgcn_cvt_pkrtz(sc0[4 * c + 0], sc0[4 * c + 1]);
                auto hi = __builtin_amdgcn_cvt_pkrtz(sc0[4 * c + 2], sc0[4 * c + 3]);
                e0[c] = __builtin_bit_cast(int, lo);
                e1[c] = __builtin_bit_cast(int, hi);
            }
#pragma unroll
            for (int ks = 0; ks < 2; ++ks) {
                int a0 = e0[2 * ks], b0 = e0[2 * ks + 1];
                int a1 = e1[2 * ks], b1 = e1[2 * ks + 1];
                asm("v_permlane32_swap_b32 %0, %1" : "+v"(a0), "+v"(b0));
                asm("v_permlane32_swap_b32 %0, %1" : "+v"(a1), "+v"(b1));
                i32x4 w = {a0, a1, b0, b1};
                pa[ks] = __builtin_bit_cast(f16x8, w);
            }
#pragma unroll
            for (int c = 0; c < 4; ++c) {
                auto lo = __builtin_amdgcn_cvt_pkrtz(sc1[4 * c + 0], sc1[4 * c + 1]);
                auto hi = __builtin_amdgcn_cvt_pkrtz(sc1[4 * c + 2], sc1[4 * c + 3]);
                e0[c] = __builtin_bit_cast(int, lo);
                e1[c] = __builtin_bit_cast(int, hi);
            }
#pragma unroll
            for (int ks = 0; ks < 2; ++ks) {
                int a0 = e0[2 * ks], b0 = e0[2 * ks + 1];
                int a1 = e1[2 * ks], b1 = e1[2 * ks + 1];
                asm("v_permlane32_swap_b32 %0, %1" : "+v"(a0), "+v"(b0));
                asm("v_permlane32_swap_b32 %0, %1" : "+v"(a1), "+v"(b1));
                i32x4 w = {a0, a1, b0, b1};
                pa[2 + ks] = __builtin_bit_cast(f16x8, w);
            }
        }

        // O^T += V^T P^T: A = V^T[d][t] from Vl (ready since barrier A), B = pa
        __builtin_amdgcn_s_setprio(1);
#pragma unroll
        for (int kk = 0; kk < 4; ++kk) {
            const int col = (kk * 16 + h * 8) ^ sxv;
#pragma unroll
            for (int db = 0; db < 4; ++db) {
                f16x8 vf = *(const f16x8*)&Vl[db * 32 + l31][col];
                accO[db] = MFMA32(vf, pa[kk], accO[db]);
            }
        }
        __builtin_amdgcn_s_setprio(0);

        // barrier B: all waves done reading Kl[kb] and Vl -> safe to overwrite
        asm volatile("s_waitcnt lgkmcnt(0)" ::: "memory");
        __builtin_amdgcn_s_barrier();
        __builtin_amdgcn_sched_barrier(0);
        if (tile + 1 < NT) {
            const f16* Vn = Vbase + (size_t)(tile + 1) * TE;
#pragma unroll
            for (int j = 0; j < 4; ++j) {
                const int c8 = (j * 256 + tid) * 8;
                gload16(Vn + c8, &Vl[0][0] + c8);
            }
        }
        if (tile + 2 < NT) {
            const f16* Kn = Kbase + (size_t)(tile + 2) * TE;
            f16* Kd = &Kl[kb][0][0];
#pragma unroll
            for (int j = 0; j < 4; ++j) {
                const int c8 = (j * 256 + tid) * 8;
                gload16(Kn + c8, Kd + c8);
            }
        }
    }

    // epilogue: lane holds O[q=l31][d = db*32 + 8c + 4h + r] -> f16x4 stores
    const float rl = 1.f / l_run;
    f16* orow = outp + ((size_t)bh * Sc + qr0 + l31) * Dc;
#pragma unroll
    for (int db = 0; db < 4; ++db) {
#pragma unroll
        for (int c = 0; c < 4; ++c) {
            const int d0 = db * 32 + c * 8 + h * 4;
            if (d0 < Dc) {
                f16x4 o;
#pragma unroll
                for (int r = 0; r < 4; ++r)
                    o[r] = (f16)(accO[db][4 * c + r] * rl);
                *(f16x4*)(orow + d0) = o;
            }
        }
    }
}

// ---------------- launcher ----------------
extern "C" void kernel_launch(void* const* d_in, const int* in_sizes, int n_in,
                              void* d_out, int out_size, void* d_ws, size_t ws_size,
                              hipStream_t stream) {
    const float* x     = (const float*)d_in[0];
    const float* alibi = (const float*)d_in[1];
    const float* amask = (const float*)d_in[2];
    const float* wq    = (const float*)d_in[3];
    const float* wk    = (const float*)d_in[4];
    const float* wv    = (const float*)d_in[5];
    const float* wo    = (const float*)d_in[6];
    const int*   lidx  = (const int*)d_in[7];
    float* out = (float*)d_out;

    char* p = (char*)d_ws;
    auto carve = [&](size_t bytes) {
        char* q = p;
        p += (bytes + 255) & ~size_t(255);
        return q;
    };
    f16* x16  = (f16*)carve((size_t)(Bc * Sc) * LDK * 2);        // 8192 x 1216
    f16* wq16 = (f16*)carve((size_t)NWP * LDK * 2);              // wq/wk/wv contiguous!
    f16* wk16 = (f16*)carve((size_t)NWP * LDK * 2);              // (1280*1216*2 = 256-aligned)
    f16* wv16 = (f16*)carve((size_t)NWP * LDK * 2);
    f16* wo16 = (f16*)carve((size_t)NWP * LDK * 2);
    f16* QpL  = (f16*)carve((size_t)BH * Sc * DP * 2);           // (bh,s,128) linear
    f16* KpT  = (f16*)carve((size_t)BH * NT * TE * 2);           // swizzled tiles
    f16* VpT  = (f16*)carve((size_t)BH * NT * TE * 2);           // swizzled tiles
    f16* comb = (f16*)carve((size_t)BH * Sc * Dc * 2 + 4096);    // + overrun slack

    // 1) merged prep: x cvt + 4 w cvts + vectorized Q/K/V pads, one dispatch
    prep_kernel<<<dim3(NBX + NBW + NBQK + NBV2), 256, 0, stream>>>(
        x, wq, wk, wv, wo, x16, wq16, wk16, wv16, wo16,
        QpL, KpT, VpT, alibi, amask, lidx);
    // 2) fused QKV projection: 256^2 GEMM, 480 blocks = 8 XCD x 4 rows x 15 cols
    gemm256_kernel<<<dim3(480), 512, 0, stream>>>(x16, LDK, wq16, QpL, KpT, VpT, nullptr, 32, 0);
    // 3) fused attention (768 blocks x 256 threads, XCD-swizzled)
    attn_kernel<<<dim3(768), 256, 0, stream>>>(QpL, KpT, VpT, lidx, comb);
    // 4) output projection: 160 blocks = 8 XCD x 4 rows x 5 cols (reads comb as
    //    8192x1200; row overrun lands on wo16's zero K-columns)
    gemm256_kernel<<<dim3(160), 512, 0, stream>>>(comb, HIDc, wo16, nullptr, nullptr, nullptr, out, 32, 1);
}

// Round 19
// 251.120 us; speedup vs baseline: 1.0130x; 1.0130x over previous
//
#include <hip/hip_runtime.h>

typedef _Float16 f16;
typedef __attribute__((ext_vector_type(8)))  _Float16 f16x8;
typedef __attribute__((ext_vector_type(4)))  _Float16 f16x4;
typedef __attribute__((ext_vector_type(4)))  float    f32x4;
typedef __attribute__((ext_vector_type(16))) float    f32x16;
typedef __attribute__((ext_vector_type(4)))  int      i32x4;

#define MFMA_F16(a,b,c) __builtin_amdgcn_mfma_f32_16x16x32_f16((a),(b),(c),0,0,0)
#define MFMA32(a,b,c)   __builtin_amdgcn_mfma_f32_32x32x16_f16((a),(b),(c),0,0,0)
#define EXP2(x)         __builtin_amdgcn_exp2f(x)   // bare v_exp_f32 (no OCML wrapper)

// problem constants
constexpr int Bc   = 4;
constexpr int Sc   = 2048;
constexpr int Hc   = 12;
constexpr int Dc   = 100;
constexpr int HIDc = 1200;
constexpr int BH   = Bc * Hc;    // 48
constexpr int DP   = 128;        // padded head dim (dim 100 carries the bias trick)
constexpr int LDK  = 1216;       // padded inner dim for x16/w16 (19 * 64)
constexpr int NWP  = 1280;       // padded row count per weight section
constexpr int KVT  = 64;         // kv tile length
constexpr int NT   = Sc / KVT;   // 32 tiles per (b,h)
constexpr int TE   = KVT * DP;   // 8192 elems per K or V tile (16 KB)
constexpr int NKT  = LDK / 64;   // 19 K-tiles in the GEMMs

// merged prep kernel block ranges (256 threads each, exact division)
constexpr int NBX  = (Bc * Sc) * LDK / 4 / 256;       // 9728  (x convert)
constexpr int NBW1 = NWP * LDK / 4 / 256;             // 1520  (per weight)
constexpr int NBW  = 4 * NBW1;                        // 6080
constexpr int NBQK = BH * Sc * 7 / 256;               // 2688  (Q+K pads, f16x4 quads)
constexpr int NBV2 = BH * NT * 28 * 8 / 256;          // 1344  (V pads, f16x8 octets)

// async global->LDS, 16B per lane (linear dest = base + lane*16)
typedef const __attribute__((address_space(1))) void GV;
typedef __attribute__((address_space(3))) void LV;
__device__ __forceinline__ void gload16(const f16* g, f16* l) {
    __builtin_amdgcn_global_load_lds((GV*)g, (LV*)l, 16, 0, 0);
}

// ---------------- merged prep: x cvt | 4x w cvt | QK pads | V pads ----------
// Pads are VECTORIZED (R17): swizzle XORs touch only bits >=3, so 4-wide d-quads
// (K) and 8-wide t-octets (V) stay contiguous after XOR -> f16x4/f16x8 stores.
// Same bijective image as the old scalar pads; values identical.
__global__ void prep_kernel(const float* __restrict__ x,
                            const float* __restrict__ w0, const float* __restrict__ w1,
                            const float* __restrict__ w2, const float* __restrict__ w3,
                            f16* __restrict__ x16,
                            f16* __restrict__ d0p, f16* __restrict__ d1p,
                            f16* __restrict__ d2p, f16* __restrict__ d3p,
                            f16* __restrict__ q, f16* __restrict__ kT, f16* __restrict__ vT,
                            const float* __restrict__ alibi, const float* __restrict__ amask,
                            const int* __restrict__ lidx) {
    const int bid = blockIdx.x;
    if (bid < NBX) {
        // x: 8192 x 1200 fp32 -> 8192 x 1216 f16 (zero K-pad); rows all valid
        int i = bid * 256 + threadIdx.x;
        int idx = i * 4;
        int r = idx / LDK, c = idx - r * LDK;
        f16x4 o;
        if (c + 3 < HIDc) {
            float4 v = *(const float4*)(x + (size_t)r * HIDc + c);
            o[0] = (f16)v.x; o[1] = (f16)v.y; o[2] = (f16)v.z; o[3] = (f16)v.w;
        } else {
#pragma unroll
            for (int e = 0; e < 4; ++e)
                o[e] = (f16)((c + e < HIDc) ? x[(size_t)r * HIDc + c + e] : 0.f);
        }
        *(f16x4*)(x16 + idx) = o;
    } else if (bid < NBX + NBW) {
        // weights: 1200 x 1200 fp32 -> 1280 x 1216 f16 (zero pads)
        int lb = bid - NBX;
        int which = lb / NBW1;
        int i = (lb - which * NBW1) * 256 + threadIdx.x;
        const float* src = (which == 0) ? w0 : (which == 1) ? w1 : (which == 2) ? w2 : w3;
        f16* dst = (which == 0) ? d0p : (which == 1) ? d1p : (which == 2) ? d2p : d3p;
        int idx = i * 4;
        int r = idx / LDK, c = idx - r * LDK;
        f16x4 o;
        if (r < HIDc && c + 3 < HIDc) {
            float4 v = *(const float4*)(src + (size_t)r * HIDc + c);
            o[0] = (f16)v.x; o[1] = (f16)v.y; o[2] = (f16)v.z; o[3] = (f16)v.w;
        } else {
#pragma unroll
            for (int e = 0; e < 4; ++e)
                o[e] = (f16)((r < HIDc && c + e < HIDc) ? src[(size_t)r * HIDc + c + e] : 0.f);
        }
        *(f16x4*)(dst + idx) = o;
    } else if (bid < NBX + NBW + NBQK) {
        // Q+K pads: thread = (rs, quad). d0 = 100 + 4*qd covers d in [100,128).
        // Q linear: {1,0,0,0} at d0==100 else zeros. K swizzled: quad stays
        // contiguous under XOR (bits>=3 only); elem0 = bias when d0==100.
        int i = (bid - NBX - NBW) * 256 + threadIdx.x;
        int qd = i % 7;
        int rs = i / 7;                             // bh*S + t
        int d0 = Dc + 4 * qd;                       // 100,104,...,124
        int bh = rs >> 11, t = rs & (Sc - 1);
        f16x4 oq = {(f16)0.f, (f16)0.f, (f16)0.f, (f16)0.f};
        f16x4 ok = {(f16)0.f, (f16)0.f, (f16)0.f, (f16)0.f};
        if (qd == 0) {
            int b = bh / Hc;
            float bias = alibi[rs] * 0.1f + amask[b * Sc + t] * ((float)(lidx[0] + 1) * 0.1f);
            oq[0] = (f16)1.0f;
            ok[0] = (f16)bias;
        }
        *(f16x4*)(q + (size_t)rs * DP + d0) = oq;
        const size_t tb = ((size_t)bh * NT + (t >> 6)) * TE;
        *(f16x4*)(kT + tb + (t & 63) * DP + (d0 ^ ((t & 15) << 3))) = ok;
    } else {
        // V pads: thread = (bh, tile, d, t-octet); zero f16x8, octet contiguous
        // under XOR ((d&7)<<3 flips bits 3-5 of t).
        int i = (bid - NBX - NBW - NBQK) * 256 + threadIdx.x;
        int oct  = i & 7;
        int rest = i >> 3;
        int d28  = rest % 28;
        int r2   = rest / 28;
        int tile = r2 & (NT - 1);
        int bh   = r2 >> 5;
        int d    = Dc + d28;
        const size_t tb = ((size_t)bh * NT + tile) * TE;
        f16x8 z = {(f16)0.f, (f16)0.f, (f16)0.f, (f16)0.f,
                   (f16)0.f, (f16)0.f, (f16)0.f, (f16)0.f};
        *(f16x8*)(vT + tb + d * 64 + ((oct * 8) ^ ((d & 7) << 3))) = z;
    }
}

// ---------------- 256x256 deep-pipelined B^T GEMM (T3 schedule) -------------
// EXACT R17 (best measured): L2-optimal A-band mapping; mfma(af, bf, acc);
// epilogue m = ...+g*4+r, n = ...+n15. K fixed = 1216 (19 tiles).
// (R18's operand-swapped epilogue was correct but marginally slower -> reverted.)
// mode 0: fused QKV scatter (B = [wq16;wk16;wv16], N=3840)
// mode 1: f32 row-major M x 1200 (final out)
__launch_bounds__(512)
__global__ void gemm256_kernel(const f16* __restrict__ A, int lda,
                               const f16* __restrict__ Bm,
                               f16* __restrict__ outQ,
                               f16* __restrict__ outK,
                               f16* __restrict__ outV,
                               float* __restrict__ oF,
                               int nbx, int mode) {
    __shared__ f16 As[2][256][64];   // 64 KB
    __shared__ f16 Bs[2][256][64];   // 64 KB

    const int tid  = threadIdx.x;
    const int lane = tid & 63, wid = tid >> 6;
    const int wm = wid >> 2, wn = wid & 3;       // 2x4 wave grid, 128x64 per wave
    const int n15 = lane & 15, g = lane >> 4;
    const int sx  = (n15 & 7) << 3;              // read-side XOR (row&7 == n15&7)

    // XCD A-band mapping (bijective): bx = xcd*4 + (s&3), by = s>>2
    const int s  = (int)blockIdx.x >> 3;
    const int bx = ((int)blockIdx.x & 7) * 4 + (s & 3);
    const int by = s >> 2;
    const int brow = bx * 256, bcol = by * 256;

    f32x4 acc[8][4];
#pragma unroll
    for (int i = 0; i < 8; ++i)
#pragma unroll
        for (int j = 0; j < 4; ++j)
            acc[i][j] = (f32x4){0.f, 0.f, 0.f, 0.f};

    const f16* Ab = A  + (size_t)brow * lda;
    const f16* Bb = Bm + (size_t)bcol * LDK;

    // prologue: stage tile 0 into buf 0 (A 4 chunks + B 4 chunks per thread)
#pragma unroll
    for (int j = 0; j < 4; ++j) {
        const int c = j * 512 + tid;             // 2048 chunks of 16B
        const int row = c >> 3;
        const int co  = ((c & 7) ^ (row & 7)) * 8;
        gload16(Ab + (size_t)row * lda + co, &As[0][0][0] + c * 8);
    }
#pragma unroll
    for (int j = 0; j < 4; ++j) {
        const int c = j * 512 + tid;
        const int row = c >> 3;
        const int co  = ((c & 7) ^ (row & 7)) * 8;
        gload16(Bb + (size_t)row * LDK + co, &Bs[0][0][0] + c * 8);
    }

    for (int kt = 0; kt < NKT; ++kt) {
        const int bsel = kt & 1;
        const int k1 = (kt + 1) << 6;
        // iteration entry: tile kt's 8 loads landed (all waves), prev reads done
        asm volatile("s_waitcnt vmcnt(0)" ::: "memory");
        __builtin_amdgcn_s_barrier();
        __builtin_amdgcn_sched_barrier(0);

#pragma unroll
        for (int ph = 0; ph < 4; ++ph) {
            const int mh = ph >> 1, nh = ph & 1;
            if (ph) __builtin_amdgcn_s_barrier();

            // ds_read this quadrant's fragments (compiler emits fine lgkmcnt)
            f16x8 af[2][4], bf[2][2];
#pragma unroll
            for (int kc = 0; kc < 2; ++kc) {
                const int col = (kc * 32 + g * 8) ^ sx;
#pragma unroll
                for (int mf = 0; mf < 4; ++mf)
                    af[kc][mf] = *(const f16x8*)&As[bsel][wm * 128 + mh * 64 + mf * 16 + n15][col];
#pragma unroll
                for (int nf = 0; nf < 2; ++nf)
                    bf[kc][nf] = *(const f16x8*)&Bs[bsel][wn * 64 + nh * 32 + nf * 16 + n15][col];
            }

            // stage next K-tile early (phases 0-1) into buf^1
            if (kt + 1 < NKT) {
                if (ph == 0) {
#pragma unroll
                    for (int j = 0; j < 4; ++j) {
                        const int c = j * 512 + tid;
                        const int row = c >> 3;
                        const int co  = ((c & 7) ^ (row & 7)) * 8;
                        gload16(Ab + (size_t)row * lda + k1 + co, &As[bsel ^ 1][0][0] + c * 8);
                    }
                } else if (ph == 1) {
#pragma unroll
                    for (int j = 0; j < 4; ++j) {
                        const int c = j * 512 + tid;
                        const int row = c >> 3;
                        const int co  = ((c & 7) ^ (row & 7)) * 8;
                        gload16(Bb + (size_t)row * LDK + k1 + co, &Bs[bsel ^ 1][0][0] + c * 8);
                    }
                }
            }

            __builtin_amdgcn_s_setprio(1);
#pragma unroll
            for (int kc = 0; kc < 2; ++kc)
#pragma unroll
                for (int mf = 0; mf < 4; ++mf)
#pragma unroll
                    for (int nf = 0; nf < 2; ++nf)
                        acc[mh * 4 + mf][nh * 2 + nf] =
                            MFMA_F16(af[kc][mf], bf[kc][nf], acc[mh * 4 + mf][nh * 2 + nf]);
            __builtin_amdgcn_s_setprio(0);
        }
    }

    // epilogue — C/D frag: row = 4*g + r, col = n15
#pragma unroll
    for (int mi = 0; mi < 8; ++mi) {
        const int m0 = brow + wm * 128 + mi * 16 + g * 4;  // 4-aligned
        const int b  = m0 >> 11;
        const int s0 = m0 & (Sc - 1);
#pragma unroll
        for (int ni = 0; ni < 4; ++ni) {
            const int n = bcol + wn * 64 + ni * 16 + n15;
            if (mode == 1) {
                if (n >= HIDc) continue;
                float* dst = oF + (size_t)m0 * HIDc + n;
#pragma unroll
                for (int r = 0; r < 4; ++r)
                    dst[r * HIDc] = acc[mi][ni][r];
            } else {
                const int which = (n >= 2560) ? 2 : (n >= 1280 ? 1 : 0);
                const int nn = n - which * 1280;
                if (nn >= HIDc) continue;
                const int h = nn / 100, d = nn - h * 100;
                if (which == 0) {
                    f16* dst = outQ + ((size_t)(b * Hc + h) * Sc + s0) * DP + d;
#pragma unroll
                    for (int r = 0; r < 4; ++r)
                        dst[r * DP] = (f16)acc[mi][ni][r];
                } else if (which == 1) {
                    const size_t tb = ((size_t)(b * Hc + h) * NT + (s0 >> 6)) * TE;
#pragma unroll
                    for (int r = 0; r < 4; ++r) {
                        const int t = s0 + r;              // same tile for r=0..3
                        outK[tb + (t & 63) * DP + (d ^ ((t & 15) << 3))] = (f16)acc[mi][ni][r];
                    }
                } else {
                    const size_t tb = ((size_t)(b * Hc + h) * NT + (s0 >> 6)) * TE;
                    f16x4 pk;
#pragma unroll
                    for (int r = 0; r < 4; ++r) pk[r] = (f16)acc[mi][ni][r];
                    *(f16x4*)(outV + tb + d * 64 + ((s0 & 63) ^ ((d & 7) << 3))) = pk;
                }
            }
        }
    }
}

// ---------------- fused flash attention (R13-exact, proven 116us) -----------
// grid 768 1-D, XCD-swizzled. 4 waves/block, 32 q-rows each (q = lane&31).
// 2 barriers/tile: K double-buffered (2 tiles slack), V single (1 tile slack).
// Queue ledger at tile-t entry: {K(t) 4, V(t) 4, K(t+1) 4} -> vmcnt(4).
// NOTE (R14 lesson): unified VGPR+AGPR footprint ~150 regs -> occupancy is
// register-bound at 3 waves/SIMD; launch_bounds(256,3) is the optimum. Do NOT
// request higher waves/EU (R14's (512,6) spilled accO to scratch: 12x slower).
__launch_bounds__(256, 3)
__global__ void attn_kernel(const f16* __restrict__ Qp, const f16* __restrict__ KpT,
                            const f16* __restrict__ VpT, const int* __restrict__ lidx,
                            f16* __restrict__ outp) {
    __shared__ f16 Kl[2][64][128];     // 32 KB, double-buffered, 4-bit swizzle
    __shared__ f16 Vl[128][64];        // 16 KB, 3-bit swizzle

    const int tid  = threadIdx.x;
    const int lane = tid & 63, wave = tid >> 6;
    const int l31 = lane & 31, h = lane >> 5;
    const int sxk = (l31 & 15) << 3;   // K read XOR ((t&15) == (l31&15))
    const int sxv = (l31 & 7) << 3;    // V read XOR ((d&7) == (l31&7))

    const int bid = blockIdx.x;
    const int bh  = (bid & 7) * 6 + ((bid >> 3) >> 4);
    const int qt  = (bid >> 3) & 15;
    const int qr0 = qt * 128 + wave * 32;

    // log2-domain scale: exp(s*10/(L+1)) == exp2(s*10*log2e/(L+1))
    const float scale = 10.f * 1.44269504f / (float)(lidx[0] + 1);

    // Q rows in regs: 7 K-steps cover d=0..111 (d>=112 is structurally zero)
    const f16* Qb = Qp + ((size_t)bh * Sc + qr0 + l31) * DP + h * 8;
    f16x8 qreg[7];
#pragma unroll
    for (int st = 0; st < 7; ++st) {
        f16x8 v = *(const f16x8*)(Qb + st * 16);
#pragma unroll
        for (int e = 0; e < 8; ++e)
            v[e] = (f16)((float)v[e] * scale);
        qreg[st] = v;
    }

    float m_run = -1e30f, l_run = 0.f;
    f32x16 accO[4];                    // O^T block db: d = db*32+(reg&3)+8*(reg>>2)+4h, q=l31
#pragma unroll
    for (int db = 0; db < 4; ++db)
#pragma unroll
        for (int i = 0; i < 16; ++i)
            accO[db][i] = 0.f;

    const f16* Kbase = KpT + (size_t)bh * NT * TE;
    const f16* Vbase = VpT + (size_t)bh * NT * TE;

    // prologue: K0 -> Kl[0], V0 -> Vl, K1 -> Kl[1]
#pragma unroll
    for (int j = 0; j < 4; ++j) {
        const int c8 = (j * 256 + tid) * 8;
        gload16(Kbase + c8, &Kl[0][0][0] + c8);
    }
#pragma unroll
    for (int j = 0; j < 4; ++j) {
        const int c8 = (j * 256 + tid) * 8;
        gload16(Vbase + c8, &Vl[0][0] + c8);
    }
#pragma unroll
    for (int j = 0; j < 4; ++j) {
        const int c8 = (j * 256 + tid) * 8;
        gload16(Kbase + TE + c8, &Kl[1][0][0] + c8);
    }

    for (int tile = 0; tile < NT; ++tile) {
        const int kb = tile & 1;

        // barrier A: K(t)+V(t) complete (leave K(t+1)'s 4 in flight)
        if (tile == NT - 1) asm volatile("s_waitcnt vmcnt(0)" ::: "memory");
        else                asm volatile("s_waitcnt vmcnt(4)" ::: "memory");
        __builtin_amdgcn_s_barrier();
        __builtin_amdgcn_sched_barrier(0);

        // S^T = K Q^T: lane q=l31, t = tb*32+(reg&3)+8*(reg>>2)+4h
        f32x16 sc0, sc1;
#pragma unroll
        for (int i = 0; i < 16; ++i) { sc0[i] = 0.f; sc1[i] = 0.f; }
        __builtin_amdgcn_s_setprio(1);
#pragma unroll
        for (int st = 0; st < 7; ++st) {
            const int col = (st * 16 + h * 8) ^ sxk;
            f16x8 kf0 = *(const f16x8*)&Kl[kb][l31][col];
            f16x8 kf1 = *(const f16x8*)&Kl[kb][32 + l31][col];
            sc0 = MFMA32(kf0, qreg[st], sc0);
            sc1 = MFMA32(kf1, qreg[st], sc1);
        }
        __builtin_amdgcn_s_setprio(0);

        // tile max via max3 tree (identical fmax semantics, 5-level depth)
        float mx0 = fmaxf(fmaxf(sc0[0], sc0[1]), sc0[2]);
        float mx1 = fmaxf(fmaxf(sc0[3], sc0[4]), sc0[5]);
        float mx2 = fmaxf(fmaxf(sc0[6], sc0[7]), sc0[8]);
        float mx3 = fmaxf(fmaxf(sc0[9], sc0[10]), sc0[11]);
        float mx4 = fmaxf(fmaxf(sc0[12], sc0[13]), sc0[14]);
        float mx5 = fmaxf(fmaxf(sc0[15], sc1[0]), sc1[1]);
        float mx6 = fmaxf(fmaxf(sc1[2], sc1[3]), sc1[4]);
        float mx7 = fmaxf(fmaxf(sc1[5], sc1[6]), sc1[7]);
        float mx8 = fmaxf(fmaxf(sc1[8], sc1[9]), sc1[10]);
        float mx9 = fmaxf(fmaxf(sc1[11], sc1[12]), sc1[13]);
        float mxa = fmaxf(sc1[14], sc1[15]);
        float nb0 = fmaxf(fmaxf(mx0, mx1), mx2);
        float nb1 = fmaxf(fmaxf(mx3, mx4), mx5);
        float nb2 = fmaxf(fmaxf(mx6, mx7), mx8);
        float nb3 = fmaxf(mx9, mxa);
        float tm = fmaxf(fmaxf(nb0, nb1), fmaxf(nb2, nb3));
        tm = fmaxf(tm, __shfl_xor(tm, 32));

        // defer-max (T13): rescale only when max grew by >8 (log2 domain)
        if (__any(tm > m_run + 8.f)) {
            const float mn = fmaxf(m_run, tm);
            const float al = EXP2(m_run - mn);
            m_run = mn;
            l_run *= al;
#pragma unroll
            for (int db = 0; db < 4; ++db) accO[db] *= al;
        }

        // P = exp2(s - m) in place; row-sum over all 64 t
        float ps = 0.f;
#pragma unroll
        for (int i = 0; i < 16; ++i) { sc0[i] = EXP2(sc0[i] - m_run); ps += sc0[i]; }
#pragma unroll
        for (int i = 0; i < 16; ++i) { sc1[i] = EXP2(sc1[i] - m_run); ps += sc1[i]; }
        ps += __shfl_xor(ps, 32);
        l_run += ps;

        // pack P -> PV B-frags: cvt_pkrtz + v_permlane32_swap_b32 (in-register)
        f16x8 pa[4];
        {
            int e0[4], e1[4];
#pragma unroll
            for (int c = 0; c < 4; ++c) {
                auto lo = __builtin_amdgcn_cvt_pkrtz(sc0[4 * c + 0], sc0[4 * c + 1]);
                auto hi = __builtin_amdgcn_cvt_pkrtz(sc0[4 * c + 2], sc0[4 * c + 3]);
                e0[c] = __builtin_bit_cast(int, lo);
                e1[c] = __builtin_bit_cast(int, hi);
            }
#pragma unroll
            for (int ks = 0; ks < 2; ++ks) {
                int a0 = e0[2 * ks], b0 = e0[2 * ks + 1];
                int a1 = e1[2 * ks], b1 = e1[2 * ks + 1];
                asm("v_permlane32_swap_b32 %0, %1" : "+v"(a0), "+v"(b0));
                asm("v_permlane32_swap_b32 %0, %1" : "+v"(a1), "+v"(b1));
                i32x4 w = {a0, a1, b0, b1};
                pa[ks] = __builtin_bit_cast(f16x8, w);
            }
#pragma unroll
            for (int c = 0; c < 4; ++c) {
                auto lo = __builtin_amdgcn_cvt_pkrtz(sc1[4 * c + 0], sc1[4 * c + 1]);
                auto hi = __builtin_amdgcn_cvt_pkrtz(sc1[4 * c + 2], sc1[4 * c + 3]);
                e0[c] = __builtin_bit_cast(int, lo);
                e1[c] = __builtin_bit_cast(int, hi);
            }
#pragma unroll
            for (int ks = 0; ks < 2; ++ks) {
                int a0 = e0[2 * ks], b0 = e0[2 * ks + 1];
                int a1 = e1[2 * ks], b1 = e1[2 * ks + 1];
                asm("v_permlane32_swap_b32 %0, %1" : "+v"(a0), "+v"(b0));
                asm("v_permlane32_swap_b32 %0, %1" : "+v"(a1), "+v"(b1));
                i32x4 w = {a0, a1, b0, b1};
                pa[2 + ks] = __builtin_bit_cast(f16x8, w);
            }
        }

        // O^T += V^T P^T: A = V^T[d][t] from Vl (ready since barrier A), B = pa
        __builtin_amdgcn_s_setprio(1);
#pragma unroll
        for (int kk = 0; kk < 4; ++kk) {
            const int col = (kk * 16 + h * 8) ^ sxv;
#pragma unroll
            for (int db = 0; db < 4; ++db) {
                f16x8 vf = *(const f16x8*)&Vl[db * 32 + l31][col];
                accO[db] = MFMA32(vf, pa[kk], accO[db]);
            }
        }
        __builtin_amdgcn_s_setprio(0);

        // barrier B: all waves done reading Kl[kb] and Vl -> safe to overwrite
        asm volatile("s_waitcnt lgkmcnt(0)" ::: "memory");
        __builtin_amdgcn_s_barrier();
        __builtin_amdgcn_sched_barrier(0);
        if (tile + 1 < NT) {
            const f16* Vn = Vbase + (size_t)(tile + 1) * TE;
#pragma unroll
            for (int j = 0; j < 4; ++j) {
                const int c8 = (j * 256 + tid) * 8;
                gload16(Vn + c8, &Vl[0][0] + c8);
            }
        }
        if (tile + 2 < NT) {
            const f16* Kn = Kbase + (size_t)(tile + 2) * TE;
            f16* Kd = &Kl[kb][0][0];
#pragma unroll
            for (int j = 0; j < 4; ++j) {
                const int c8 = (j * 256 + tid) * 8;
                gload16(Kn + c8, Kd + c8);
            }
        }
    }

    // epilogue: lane holds O[q=l31][d = db*32 + 8c + 4h + r] -> f16x4 stores
    const float rl = 1.f / l_run;
    f16* orow = outp + ((size_t)bh * Sc + qr0 + l31) * Dc;
#pragma unroll
    for (int db = 0; db < 4; ++db) {
#pragma unroll
        for (int c = 0; c < 4; ++c) {
            const int d0 = db * 32 + c * 8 + h * 4;
            if (d0 < Dc) {
                f16x4 o;
#pragma unroll
                for (int r = 0; r < 4; ++r)
                    o[r] = (f16)(accO[db][4 * c + r] * rl);
                *(f16x4*)(orow + d0) = o;
            }
        }
    }
}

// ---------------- launcher ----------------
extern "C" void kernel_launch(void* const* d_in, const int* in_sizes, int n_in,
                              void* d_out, int out_size, void* d_ws, size_t ws_size,
                              hipStream_t stream) {
    const float* x     = (const float*)d_in[0];
    const float* alibi = (const float*)d_in[1];
    const float* amask = (const float*)d_in[2];
    const float* wq    = (const float*)d_in[3];
    const float* wk    = (const float*)d_in[4];
    const float* wv    = (const float*)d_in[5];
    const float* wo    = (const float*)d_in[6];
    const int*   lidx  = (const int*)d_in[7];
    float* out = (float*)d_out;

    char* p = (char*)d_ws;
    auto carve = [&](size_t bytes) {
        char* q = p;
        p += (bytes + 255) & ~size_t(255);
        return q;
    };
    f16* x16  = (f16*)carve((size_t)(Bc * Sc) * LDK * 2);        // 8192 x 1216
    f16* wq16 = (f16*)carve((size_t)NWP * LDK * 2);              // wq/wk/wv contiguous!
    f16* wk16 = (f16*)carve((size_t)NWP * LDK * 2);              // (1280*1216*2 = 256-aligned)
    f16* wv16 = (f16*)carve((size_t)NWP * LDK * 2);
    f16* wo16 = (f16*)carve((size_t)NWP * LDK * 2);
    f16* QpL  = (f16*)carve((size_t)BH * Sc * DP * 2);           // (bh,s,128) linear
    f16* KpT  = (f16*)carve((size_t)BH * NT * TE * 2);           // swizzled tiles
    f16* VpT  = (f16*)carve((size_t)BH * NT * TE * 2);           // swizzled tiles
    f16* comb = (f16*)carve((size_t)BH * Sc * Dc * 2 + 4096);    // + overrun slack

    // 1) merged prep: x cvt + 4 w cvts + vectorized Q/K/V pads, one dispatch
    prep_kernel<<<dim3(NBX + NBW + NBQK + NBV2), 256, 0, stream>>>(
        x, wq, wk, wv, wo, x16, wq16, wk16, wv16, wo16,
        QpL, KpT, VpT, alibi, amask, lidx);
    // 2) fused QKV projection: 256^2 GEMM, 480 blocks = 8 XCD x 4 rows x 15 cols
    gemm256_kernel<<<dim3(480), 512, 0, stream>>>(x16, LDK, wq16, QpL, KpT, VpT, nullptr, 32, 0);
    // 3) fused attention (768 blocks x 256 threads, XCD-swizzled) — R13 exact
    attn_kernel<<<dim3(768), 256, 0, stream>>>(QpL, KpT, VpT, lidx, comb);
    // 4) output projection: 160 blocks = 8 XCD x 4 rows x 5 cols (reads comb as
    //    8192x1200; row overrun lands on wo16's zero K-columns)
    gemm256_kernel<<<dim3(160), 512, 0, stream>>>(comb, HIDc, wo16, nullptr, nullptr, nullptr, out, 32, 1);
}